// Round 16
// baseline (135.359 us; speedup 1.0000x reference)
//
#include <hip/hip_runtime.h>
#include <hip/hip_bf16.h>

typedef __attribute__((ext_vector_type(8))) short bf16x8;
typedef __attribute__((ext_vector_type(4))) float f32x4;

#define GSTR 68   // floats per er-row of gate buffer (32 f x 2 + 4 pad)

__device__ __forceinline__ short f2bf(float f) {
  unsigned u = __float_as_uint(f);
  u += 0x7fffu + ((u >> 16) & 1u);   // RNE to bf16
  return (short)(u >> 16);
}

__device__ __forceinline__ bf16x8 cvt8(float4 A, float4 B) {
  union { bf16x8 v; __hip_bfloat162 h[4]; } u;
  u.h[0] = __float22bfloat162_rn(make_float2(A.x, A.y));
  u.h[1] = __float22bfloat162_rn(make_float2(A.z, A.w));
  u.h[2] = __float22bfloat162_rn(make_float2(B.x, B.y));
  u.h[3] = __float22bfloat162_rn(make_float2(B.z, B.w));
  return u.v;
}

__device__ __forceinline__ bf16x8 ldsfrag(const int4* p) {
  union { int4 i; bf16x8 b; } u;
  u.i = *p;
  return u.b;
}

__device__ __forceinline__ float silu_(float x) {
  return __fdividef(x, 1.f + __expf(-x));
}

// ---- setup: pack the 14 MFMA weight-fragment tiles into d_ws (14 KB) ----
__global__ void pack_weights_kernel(
    const float* __restrict__ W1, const float* __restrict__ W2,
    const float* __restrict__ WR, const float* __restrict__ BR,
    int4* __restrict__ wsf)
{
  const int tid = threadIdx.x, wid = tid >> 6, l = tid & 63;
  const int col16 = l & 15, c = l >> 4, kc = c << 3;
  for (int t = wid; t < 14; t += 4) {
    int q[4];
    #pragma unroll
    for (int jj = 0; jj < 4; ++jj) {
      float f0, f1;
      if (t < 2) {                       // W1^T A-frags
        int k0 = kc + 2*jj;
        int co = (t << 4) + col16;
        f0 = W1[k0*32 + co]; f1 = W1[(k0+1)*32 + co];
      } else if (t < 8) {                // W2 B-frags, k permuted by pi(c,j)
        int j0 = 2*jj;
        int feat = (j0 < 4) ? (4*c + j0) : (16 + 4*c + (j0 - 4));
        int co = ((t-2) << 4) + col16;
        f0 = W2[feat*96 + co]; f1 = W2[(feat+1)*96 + co];
      } else {                           // WR B-frags, row20 = BR
        int k0 = kc + 2*jj;
        int co = ((t-8) << 4) + col16;
        f0 = (k0   < 20) ? WR[k0*96 + co]     : ((k0   == 20) ? BR[co] : 0.f);
        f1 = (k0+1 < 20) ? WR[(k0+1)*96 + co] : ((k0+1 == 20) ? BR[co] : 0.f);
      }
      q[jj] = ((int)(unsigned short)f2bf(f0)) |
              (((int)(unsigned short)f2bf(f1)) << 16);
    }
    wsf[t*64 + l] = make_int4(q[0], q[1], q[2], q[3]);
  }
}

// ---- main: v15 (one wave per node, barrier-free redundant weight
// staging, predicated loads skipping dead edges, glds redistribution)
// + hoisted half-1 V prefetch: BOTH halves' V tiles (vva/vvb) and dir
// words issue in the prologue, so the load queue stays full across the
// whole wave instead of ~half of it. Straight-line, no backedge. ----
__global__ __launch_bounds__(256, 3) void deepdft_v16(
    const float* __restrict__ S, const float* __restrict__ V,
    const float* __restrict__ EXPN, const float* __restrict__ DIR,
    const float* __restrict__ MASK, const float* __restrict__ DIST,
    const float* __restrict__ B1, const float* __restrict__ B2,
    const int4* __restrict__ wsf,
    float* __restrict__ OUT, int n_nodes)
{
  __shared__ int4  wlds[14][64];
  __shared__ float glds[4][16 * GSTR];   // per-wave gate buffer (ga,gc pairs)

  const int tid = threadIdx.x, wid = tid >> 6, l = tid & 63;
  const int col16 = l & 15, c = l >> 4, kc = c << 3;
  const int er8 = l >> 2, fo = l & 3;    // V-phase lane mapping

  int n = blockIdx.x * 4 + wid;
  if (n >= n_nodes) n = n_nodes - 1;
  const int eb0 = n << 5, eb1 = eb0 + 16;

  // ---- gate inputs for all 32 edges + both halves' dir ----
  float dvB  = DIST[eb0 + (l & 31)];
  float mvB  = MASK[eb0 + (l & 31)];
  float drv0 = DIR[(size_t)eb0 * 3 + (l < 48 ? l : 47)];
  float drv1 = DIR[(size_t)eb1 * 3 + (l < 48 ? l : 47)];

  // biases (tiny, L3-hot)
  f32x4 b1a, b1b;
  {
    float4 t0 = *reinterpret_cast<const float4*>(B1 + 4*c);
    float4 t1 = *reinterpret_cast<const float4*>(B1 + 16 + 4*c);
    b1a[0]=t0.x; b1a[1]=t0.y; b1a[2]=t0.z; b1a[3]=t0.w;
    b1b[0]=t1.x; b1b[1]=t1.y; b1b[2]=t1.z; b1b[3]=t1.w;
  }
  float b2v[6];
  #pragma unroll
  for (int t = 0; t < 6; ++t) b2v[t] = B2[(t << 4) + col16];

  // per-lane gate for all 32 edges (lane l&31 -> edge eb0+(l&31))
  float wvB = 0.f;
  if (dvB < 5.f) wvB = mvB * 0.5f * (__cosf(0.62831853071795865f * dvB) + 1.f);

  // ---- staged regs, zero-init so dead lanes hold exact zeros ----
  const float4 z4 = make_float4(0.f, 0.f, 0.f, 0.f);
  float4 sS0 = z4, sS1 = z4, sE0 = z4;
  float4 sE1 = (c == 2) ? make_float4(1.f, 0.f, 0.f, 0.f) : z4; // k=20 -> +br
  float4 vva[6], vvb[6];
  #pragma unroll
  for (int j = 0; j < 6; ++j) { vva[j] = z4; vvb[j] = z4; }

  auto issueS = [&](int eb) {
    const float* sp = S + (size_t)(eb + col16) * 32 + kc;
    sS0 = *reinterpret_cast<const float4*>(sp);
    sS1 = *reinterpret_cast<const float4*>(sp + 4);
    const float* ep = EXPN + (size_t)(eb + col16) * 20;
    if (c < 2) {
      sE0 = *reinterpret_cast<const float4*>(ep + kc);
      sE1 = *reinterpret_cast<const float4*>(ep + kc + 4);
    } else if (c == 2) {
      sE0 = *reinterpret_cast<const float4*>(ep + 16);   // sE1 keeps {1,0,0,0}
    }
  };
  auto issueV = [&](int eb, float4 (&vv)[6]) {
    const float* vb = V + (size_t)(eb + er8) * 96 + fo * 8;
    vv[0] = *reinterpret_cast<const float4*>(vb);
    vv[1] = *reinterpret_cast<const float4*>(vb + 4);
    vv[2] = *reinterpret_cast<const float4*>(vb + 32);
    vv[3] = *reinterpret_cast<const float4*>(vb + 36);
    vv[4] = *reinterpret_cast<const float4*>(vb + 64);
    vv[5] = *reinterpret_cast<const float4*>(vb + 68);
  };

  // ---- predicated prologue loads: half-0 S + BOTH halves' V ----
  { float p = __shfl(wvB, col16);    if (p != 0.f) issueS(eb0); }
  { float p = __shfl(wvB, er8);      if (p != 0.f) issueV(eb0, vva); }
  { float p = __shfl(wvB, 16 + er8); if (p != 0.f) issueV(eb1, vvb); }

  // ---- stage ALL weight tiles per wave (redundant, identical values,
  // L2-hot) -> wave-internal lgkm ordering only, NO __syncthreads ----
  #pragma unroll
  for (int t = 0; t < 14; ++t) wlds[t][l] = wsf[t*64 + l];

  float part[24];
  #pragma unroll
  for (int q = 0; q < 24; ++q) part[q] = 0.f;
  float accs0 = 0.f, accs1 = 0.f;
  float* gw = &glds[wid][0];
  const f32x4 z = {0.f, 0.f, 0.f, 0.f};

  // ================= one 16-edge half =================
  auto gate_phase = [&](int woff, bool pfS) {
    bf16x8 bs = cvt8(sS0, sS1);
    bf16x8 ae = cvt8(sE0, sE1);
    if (pfS) {                                  // predicated S prefetch (h1)
      float p = __shfl(wvB, 16 + col16);
      if (p != 0.f) issueS(eb1);
    }

    f32x4 h0 = __builtin_amdgcn_mfma_f32_16x16x32_bf16(ldsfrag(&wlds[0][l]), bs, b1a, 0,0,0);
    f32x4 h1 = __builtin_amdgcn_mfma_f32_16x16x32_bf16(ldsfrag(&wlds[1][l]), bs, b1b, 0,0,0);
    bf16x8 ah;
    {
      union { bf16x8 v; __hip_bfloat162 h[4]; } u;
      u.h[0] = __float22bfloat162_rn(make_float2(silu_(h0[0]), silu_(h0[1])));
      u.h[1] = __float22bfloat162_rn(make_float2(silu_(h0[2]), silu_(h0[3])));
      u.h[2] = __float22bfloat162_rn(make_float2(silu_(h1[0]), silu_(h1[1])));
      u.h[3] = __float22bfloat162_rn(make_float2(silu_(h1[2]), silu_(h1[3])));
      ah = u.v;
    }

    float wv0 = __shfl(wvB, woff + 4*c + 0);
    float wv1 = __shfl(wvB, woff + 4*c + 1);
    float wv2 = __shfl(wvB, woff + 4*c + 2);
    float wv3 = __shfl(wvB, woff + 4*c + 3);

    #pragma unroll
    for (int tt = 0; tt < 2; ++tt) {
      f32x4 rA = __builtin_amdgcn_mfma_f32_16x16x32_bf16(ae, ldsfrag(&wlds[ 8+tt][l]), z, 0,0,0);
      f32x4 rB = __builtin_amdgcn_mfma_f32_16x16x32_bf16(ae, ldsfrag(&wlds[10+tt][l]), z, 0,0,0);
      f32x4 rC = __builtin_amdgcn_mfma_f32_16x16x32_bf16(ae, ldsfrag(&wlds[12+tt][l]), z, 0,0,0);
      f32x4 lA = __builtin_amdgcn_mfma_f32_16x16x32_bf16(ah, ldsfrag(&wlds[ 2+tt][l]), z, 0,0,0);
      f32x4 lB = __builtin_amdgcn_mfma_f32_16x16x32_bf16(ah, ldsfrag(&wlds[ 4+tt][l]), z, 0,0,0);
      f32x4 lC = __builtin_amdgcn_mfma_f32_16x16x32_bf16(ah, ldsfrag(&wlds[ 6+tt][l]), z, 0,0,0);
      #pragma unroll
      for (int r = 0; r < 4; ++r) {
        const float wv = (r==0) ? wv0 : (r==1) ? wv1 : (r==2) ? wv2 : wv3;
        const float ga = wv * (lA[r] + b2v[tt])   * rA[r];
        const float gb = wv * (lB[r] + b2v[2+tt]) * rB[r];
        const float gc = wv * (lC[r] + b2v[4+tt]) * rC[r];
        if (tt == 0) accs0 += gb; else accs1 += gb;
        *reinterpret_cast<float2*>(
            &gw[(4*c + r) * GSTR + 2*(col16 + 16*tt)]) = make_float2(ga, gc);
      }
    }
    __builtin_amdgcn_wave_barrier();
  };

  auto v_phase = [&](const float4 (&vv)[6], float drvh) {
    float d0 = __shfl(drvh, 3*er8 + 0);
    float d1 = __shfl(drvh, 3*er8 + 1);
    float d2 = __shfl(drvh, 3*er8 + 2);

    float4 gp[4];
    #pragma unroll
    for (int k = 0; k < 4; ++k)
      gp[k] = *reinterpret_cast<const float4*>(&gw[er8 * GSTR + 16*fo + 4*k]);

    #pragma unroll
    for (int ax = 0; ax < 3; ++ax) {
      const float dax = (ax==0) ? d0 : (ax==1) ? d1 : d2;
      #pragma unroll
      for (int j = 0; j < 8; ++j) {
        const float vj  = vv[2*ax + (j>>2)][j&3];
        const float gaj = gp[j>>1][(j&1)*2];
        const float gcj = gp[j>>1][(j&1)*2 + 1];
        part[ax*8+j] = fmaf(vj, gaj, fmaf(dax, gcj, part[ax*8+j]));
      }
    }
    __builtin_amdgcn_wave_barrier();   // next half's gate writes stay below
  };

  gate_phase( 0, true );  v_phase(vva, drv0);   // half 0 (S(h1) prefetch inside)
  gate_phase(16, false);  v_phase(vvb, drv1);   // half 1

  // ---- reduce over er (lanes stride 4) and store ----
  #pragma unroll
  for (int q = 0; q < 24; ++q) {
    part[q] += __shfl_xor(part[q], 4);
    part[q] += __shfl_xor(part[q], 8);
    part[q] += __shfl_xor(part[q], 16);
    part[q] += __shfl_xor(part[q], 32);
  }
  accs0 += __shfl_xor(accs0, 16); accs0 += __shfl_xor(accs0, 32);
  accs1 += __shfl_xor(accs1, 16); accs1 += __shfl_xor(accs1, 32);

  if (l < 16) {
    OUT[(size_t)n * 32 + col16]      = accs0;
    OUT[(size_t)n * 32 + 16 + col16] = accs1;
  }
  if (l < 4) {
    float* ov = OUT + (size_t)n_nodes * 32 + (size_t)n * 96 + 8*fo;
    #pragma unroll
    for (int ax = 0; ax < 3; ++ax) {
      *reinterpret_cast<float4*>(ov + ax*32) =
          make_float4(part[ax*8+0], part[ax*8+1], part[ax*8+2], part[ax*8+3]);
      *reinterpret_cast<float4*>(ov + ax*32 + 4) =
          make_float4(part[ax*8+4], part[ax*8+5], part[ax*8+6], part[ax*8+7]);
    }
  }
}

extern "C" void kernel_launch(void* const* d_in, const int* in_sizes, int n_in,
                              void* d_out, int out_size, void* d_ws, size_t ws_size,
                              hipStream_t stream) {
  const float* S    = (const float*)d_in[0];
  const float* V    = (const float*)d_in[1];
  const float* EXPN = (const float*)d_in[2];
  const float* DIR  = (const float*)d_in[3];
  const float* MASK = (const float*)d_in[4];
  const float* DIST = (const float*)d_in[5];
  const float* W1   = (const float*)d_in[6];
  const float* B1   = (const float*)d_in[7];
  const float* W2   = (const float*)d_in[8];
  const float* B2   = (const float*)d_in[9];
  const float* WR   = (const float*)d_in[10];
  const float* BR   = (const float*)d_in[11];
  float* OUT = (float*)d_out;
  int4* wsf = (int4*)d_ws;   // 14 KB packed weight fragments

  const int n_nodes = in_sizes[0] / 1024;            // 30000
  const int grid = (n_nodes + 3) / 4;                // 7500

  hipLaunchKernelGGL(pack_weights_kernel, dim3(1), dim3(256), 0, stream,
                     W1, W2, WR, BR, wsf);
  hipLaunchKernelGGL(deepdft_v16, dim3(grid), dim3(256), 0, stream,
                     S, V, EXPN, DIR, MASK, DIST, B1, B2, wsf, OUT, n_nodes);
}

// Round 17
// 109.000 us; speedup vs baseline: 1.2418x; 1.2418x over previous
//
#include <hip/hip_runtime.h>
#include <hip/hip_bf16.h>

typedef __attribute__((ext_vector_type(8))) short bf16x8;
typedef __attribute__((ext_vector_type(4))) float f32x4;

#define GSTR 68   // floats per er-row of gate buffer (32 f x 2 + 4 pad)

__device__ __forceinline__ short f2bf(float f) {
  unsigned u = __float_as_uint(f);
  u += 0x7fffu + ((u >> 16) & 1u);   // RNE to bf16
  return (short)(u >> 16);
}

__device__ __forceinline__ bf16x8 cvt8(float4 A, float4 B) {
  union { bf16x8 v; __hip_bfloat162 h[4]; } u;
  u.h[0] = __float22bfloat162_rn(make_float2(A.x, A.y));
  u.h[1] = __float22bfloat162_rn(make_float2(A.z, A.w));
  u.h[2] = __float22bfloat162_rn(make_float2(B.x, B.y));
  u.h[3] = __float22bfloat162_rn(make_float2(B.z, B.w));
  return u.v;
}

__device__ __forceinline__ bf16x8 ldsfrag(const int4* p) {
  union { int4 i; bf16x8 b; } u;
  u.i = *p;
  return u.b;
}

__device__ __forceinline__ float silu_(float x) {
  return __fdividef(x, 1.f + __expf(-x));
}

// ---- setup: pack the 14 MFMA weight-fragment tiles into d_ws (14 KB) ----
__global__ void pack_weights_kernel(
    const float* __restrict__ W1, const float* __restrict__ W2,
    const float* __restrict__ WR, const float* __restrict__ BR,
    int4* __restrict__ wsf)
{
  const int tid = threadIdx.x, wid = tid >> 6, l = tid & 63;
  const int col16 = l & 15, c = l >> 4, kc = c << 3;
  for (int t = wid; t < 14; t += 4) {
    int q[4];
    #pragma unroll
    for (int jj = 0; jj < 4; ++jj) {
      float f0, f1;
      if (t < 2) {                       // W1^T A-frags
        int k0 = kc + 2*jj;
        int co = (t << 4) + col16;
        f0 = W1[k0*32 + co]; f1 = W1[(k0+1)*32 + co];
      } else if (t < 8) {                // W2 B-frags, k permuted by pi(c,j)
        int j0 = 2*jj;
        int feat = (j0 < 4) ? (4*c + j0) : (16 + 4*c + (j0 - 4));
        int co = ((t-2) << 4) + col16;
        f0 = W2[feat*96 + co]; f1 = W2[(feat+1)*96 + co];
      } else {                           // WR B-frags, row20 = BR
        int k0 = kc + 2*jj;
        int co = ((t-8) << 4) + col16;
        f0 = (k0   < 20) ? WR[k0*96 + co]     : ((k0   == 20) ? BR[co] : 0.f);
        f1 = (k0+1 < 20) ? WR[(k0+1)*96 + co] : ((k0+1 == 20) ? BR[co] : 0.f);
      }
      q[jj] = ((int)(unsigned short)f2bf(f0)) |
              (((int)(unsigned short)f2bf(f1)) << 16);
    }
    wsf[t*64 + l] = make_int4(q[0], q[1], q[2], q[3]);
  }
}

// ---- main: one wave per node. Gate-predicated loads: edges with
// mask==0 or dist>=cutoff (~33%) never load S/EXPN/V -- their whole
// cache lines are dropped via exec-mask. Dead lanes carry zeros, and
// w==0 multiplies every contribution out exactly (bit-identical to ref).
__global__ __launch_bounds__(256, 3) void deepdft_v9(
    const float* __restrict__ S, const float* __restrict__ V,
    const float* __restrict__ EXPN, const float* __restrict__ DIR,
    const float* __restrict__ MASK, const float* __restrict__ DIST,
    const float* __restrict__ B1, const float* __restrict__ B2,
    const int4* __restrict__ wsf,
    float* __restrict__ OUT, int n_nodes)
{
  __shared__ int4  wlds[14][64];
  __shared__ float glds[4][16 * GSTR];   // per-wave gate buffer (ga,gc pairs)

  const int tid = threadIdx.x, wid = tid >> 6, l = tid & 63;
  const int col16 = l & 15, c = l >> 4, kc = c << 3;
  const int er8 = l >> 2, fo = l & 3;    // V-phase lane mapping

  int n = blockIdx.x * 4 + wid;
  if (n >= n_nodes) n = n_nodes - 1;
  const int eb0 = n << 5, eb1 = eb0 + 16;

  // ---- tiny gate inputs for BOTH halves, issued first ----
  float dv0 = DIST[eb0 + col16];
  float mv0 = MASK[eb0 + col16];
  float dv1 = DIST[eb1 + col16];
  float mv1 = MASK[eb1 + col16];
  float drv = DIR[(size_t)eb0 * 3 + (l < 48 ? l : 47)];

  // ---- stage weights (4 int4 loads/wave from pre-packed d_ws) ----
  #pragma unroll
  for (int t = wid; t < 14; t += 4) wlds[t][l] = wsf[t*64 + l];

  f32x4 b1a, b1b;
  {
    float4 t0 = *reinterpret_cast<const float4*>(B1 + 4*c);
    float4 t1 = *reinterpret_cast<const float4*>(B1 + 16 + 4*c);
    b1a[0]=t0.x; b1a[1]=t0.y; b1a[2]=t0.z; b1a[3]=t0.w;
    b1b[0]=t1.x; b1b[1]=t1.y; b1b[2]=t1.z; b1b[3]=t1.w;
  }
  float b2v[6];
  #pragma unroll
  for (int t = 0; t < 6; ++t) b2v[t] = B2[(t << 4) + col16];

  // ---- per-edge gates (edge = col16 of each half) ----
  float wvl0 = 0.f, wvl1 = 0.f;
  if (dv0 < 5.f) wvl0 = mv0 * 0.5f * (__cosf(0.62831853071795865f * dv0) + 1.f);
  if (dv1 < 5.f) wvl1 = mv1 * 0.5f * (__cosf(0.62831853071795865f * dv1) + 1.f);

  // ---- staged regs, zero-init so dead lanes hold exact zeros ----
  const float4 z4 = make_float4(0.f, 0.f, 0.f, 0.f);
  float4 sS0 = z4, sS1 = z4, sE0 = z4;
  float4 sE1 = (c == 2) ? make_float4(1.f, 0.f, 0.f, 0.f) : z4; // k=20 -> +br
  float4 vva[6];
  #pragma unroll
  for (int j = 0; j < 6; ++j) vva[j] = z4;

  auto issueS = [&](int eb) {
    const float* sp = S + (size_t)(eb + col16) * 32 + kc;
    sS0 = *reinterpret_cast<const float4*>(sp);
    sS1 = *reinterpret_cast<const float4*>(sp + 4);
    const float* ep = EXPN + (size_t)(eb + col16) * 20;
    if (c < 2) {
      sE0 = *reinterpret_cast<const float4*>(ep + kc);
      sE1 = *reinterpret_cast<const float4*>(ep + kc + 4);
    } else if (c == 2) {
      sE0 = *reinterpret_cast<const float4*>(ep + 16);   // sE1 keeps {1,0,0,0}
    }
  };
  auto issueV = [&](int eb) {
    const float* vb = V + (size_t)(eb + er8) * 96 + fo * 8;
    vva[0] = *reinterpret_cast<const float4*>(vb);
    vva[1] = *reinterpret_cast<const float4*>(vb + 4);
    vva[2] = *reinterpret_cast<const float4*>(vb + 32);
    vva[3] = *reinterpret_cast<const float4*>(vb + 36);
    vva[4] = *reinterpret_cast<const float4*>(vb + 64);
    vva[5] = *reinterpret_cast<const float4*>(vb + 68);
  };

  // predicated cold-start loads for half 0
  if (wvl0 != 0.f) issueS(eb0);
  {
    float wv_er = __shfl(wvl0, er8);
    if (wv_er != 0.f) issueV(eb0);
  }

  __syncthreads();

  float part[24];
  #pragma unroll
  for (int q = 0; q < 24; ++q) part[q] = 0.f;
  float accs0 = 0.f, accs1 = 0.f;
  float* gw = &glds[wid][0];
  const f32x4 z = {0.f, 0.f, 0.f, 0.f};

  #pragma unroll
  for (int it = 0; it < 2; ++it) {
    const float wvl = it ? wvl1 : wvl0;
    // ================= gate phase (D-layout lanes) =================
    bf16x8 bs = cvt8(sS0, sS1);
    bf16x8 ae = cvt8(sE0, sE1);
    if (it == 0 && wvl1 != 0.f) issueS(eb1);   // predicated prefetch

    // hT: lane-local h row per edge
    f32x4 h0 = __builtin_amdgcn_mfma_f32_16x16x32_bf16(ldsfrag(&wlds[0][l]), bs, b1a, 0,0,0);
    f32x4 h1 = __builtin_amdgcn_mfma_f32_16x16x32_bf16(ldsfrag(&wlds[1][l]), bs, b1b, 0,0,0);
    bf16x8 ah;
    {
      union { bf16x8 v; __hip_bfloat162 h[4]; } u;
      u.h[0] = __float22bfloat162_rn(make_float2(silu_(h0[0]), silu_(h0[1])));
      u.h[1] = __float22bfloat162_rn(make_float2(silu_(h0[2]), silu_(h0[3])));
      u.h[2] = __float22bfloat162_rn(make_float2(silu_(h1[0]), silu_(h1[1])));
      u.h[3] = __float22bfloat162_rn(make_float2(silu_(h1[2]), silu_(h1[3])));
      ah = u.v;
    }

    // per-edge gate for er = 4c+r
    float wv0 = __shfl(wvl, 4*c + 0);
    float wv1 = __shfl(wvl, 4*c + 1);
    float wv2 = __shfl(wvl, 4*c + 2);
    float wv3 = __shfl(wvl, 4*c + 3);

    #pragma unroll
    for (int tt = 0; tt < 2; ++tt) {
      f32x4 rA = __builtin_amdgcn_mfma_f32_16x16x32_bf16(ae, ldsfrag(&wlds[ 8+tt][l]), z, 0,0,0);
      f32x4 rB = __builtin_amdgcn_mfma_f32_16x16x32_bf16(ae, ldsfrag(&wlds[10+tt][l]), z, 0,0,0);
      f32x4 rC = __builtin_amdgcn_mfma_f32_16x16x32_bf16(ae, ldsfrag(&wlds[12+tt][l]), z, 0,0,0);
      f32x4 lA = __builtin_amdgcn_mfma_f32_16x16x32_bf16(ah, ldsfrag(&wlds[ 2+tt][l]), z, 0,0,0);
      f32x4 lB = __builtin_amdgcn_mfma_f32_16x16x32_bf16(ah, ldsfrag(&wlds[ 4+tt][l]), z, 0,0,0);
      f32x4 lC = __builtin_amdgcn_mfma_f32_16x16x32_bf16(ah, ldsfrag(&wlds[ 6+tt][l]), z, 0,0,0);
      #pragma unroll
      for (int r = 0; r < 4; ++r) {
        const float wv = (r==0) ? wv0 : (r==1) ? wv1 : (r==2) ? wv2 : wv3;
        const float ga = wv * (lA[r] + b2v[tt])   * rA[r];
        const float gb = wv * (lB[r] + b2v[2+tt]) * rB[r];
        const float gc = wv * (lC[r] + b2v[4+tt]) * rC[r];
        if (tt == 0) accs0 += gb; else accs1 += gb;
        *reinterpret_cast<float2*>(
            &gw[(4*c + r) * GSTR + 2*(col16 + 16*tt)]) = make_float2(ga, gc);
      }
    }
    __builtin_amdgcn_wave_barrier();

    // ================= V phase (er8/fo lanes) =================
    float d0 = __shfl(drv, 3*er8 + 0);
    float d1 = __shfl(drv, 3*er8 + 1);
    float d2 = __shfl(drv, 3*er8 + 2);
    if (it == 0) drv = DIR[(size_t)eb1 * 3 + (l < 48 ? l : 47)];

    float4 gp[4];
    #pragma unroll
    for (int k = 0; k < 4; ++k)
      gp[k] = *reinterpret_cast<const float4*>(&gw[er8 * GSTR + 16*fo + 4*k]);

    #pragma unroll
    for (int ax = 0; ax < 3; ++ax) {
      const float dax = (ax==0) ? d0 : (ax==1) ? d1 : d2;
      #pragma unroll
      for (int j = 0; j < 8; ++j) {
        const float vj  = vva[2*ax + (j>>2)][j&3];
        const float gaj = gp[j>>1][(j&1)*2];
        const float gcj = gp[j>>1][(j&1)*2 + 1];
        part[ax*8+j] = fmaf(vj, gaj, fmaf(dax, gcj, part[ax*8+j]));
      }
    }
    if (it == 0) {
      float wv_er = __shfl(wvl1, er8);
      if (wv_er != 0.f) issueV(eb1);   // predicated prefetch
    }
    __builtin_amdgcn_wave_barrier();   // next item's gate writes stay below
  }

  // ---- reduce over er (lanes stride 4) and store ----
  #pragma unroll
  for (int q = 0; q < 24; ++q) {
    part[q] += __shfl_xor(part[q], 4);
    part[q] += __shfl_xor(part[q], 8);
    part[q] += __shfl_xor(part[q], 16);
    part[q] += __shfl_xor(part[q], 32);
  }
  accs0 += __shfl_xor(accs0, 16); accs0 += __shfl_xor(accs0, 32);
  accs1 += __shfl_xor(accs1, 16); accs1 += __shfl_xor(accs1, 32);

  if (l < 16) {
    OUT[(size_t)n * 32 + col16]      = accs0;
    OUT[(size_t)n * 32 + 16 + col16] = accs1;
  }
  if (l < 4) {
    float* ov = OUT + (size_t)n_nodes * 32 + (size_t)n * 96 + 8*fo;
    #pragma unroll
    for (int ax = 0; ax < 3; ++ax) {
      *reinterpret_cast<float4*>(ov + ax*32) =
          make_float4(part[ax*8+0], part[ax*8+1], part[ax*8+2], part[ax*8+3]);
      *reinterpret_cast<float4*>(ov + ax*32 + 4) =
          make_float4(part[ax*8+4], part[ax*8+5], part[ax*8+6], part[ax*8+7]);
    }
  }
}

extern "C" void kernel_launch(void* const* d_in, const int* in_sizes, int n_in,
                              void* d_out, int out_size, void* d_ws, size_t ws_size,
                              hipStream_t stream) {
  const float* S    = (const float*)d_in[0];
  const float* V    = (const float*)d_in[1];
  const float* EXPN = (const float*)d_in[2];
  const float* DIR  = (const float*)d_in[3];
  const float* MASK = (const float*)d_in[4];
  const float* DIST = (const float*)d_in[5];
  const float* W1   = (const float*)d_in[6];
  const float* B1   = (const float*)d_in[7];
  const float* W2   = (const float*)d_in[8];
  const float* B2   = (const float*)d_in[9];
  const float* WR   = (const float*)d_in[10];
  const float* BR   = (const float*)d_in[11];
  float* OUT = (float*)d_out;
  int4* wsf = (int4*)d_ws;   // 14 KB packed weight fragments

  const int n_nodes = in_sizes[0] / 1024;            // 30000
  const int grid = (n_nodes + 3) / 4;                // 7500

  hipLaunchKernelGGL(pack_weights_kernel, dim3(1), dim3(256), 0, stream,
                     W1, W2, WR, BR, wsf);
  hipLaunchKernelGGL(deepdft_v9, dim3(grid), dim3(256), 0, stream,
                     S, V, EXPN, DIR, MASK, DIST, B1, B2, wsf, OUT, n_nodes);
}